// Round 10
// baseline (258.551 us; speedup 1.0000x reference)
//
#include <hip/hip_runtime.h>
#include <stdint.h>

#define ALPHA_ 0.7f
constexpr int Tn = 256, Vn = 256, Qn = 32, Fn = 64, Dn = 512;
constexpr int Mn = Tn * Qn;   // 8192
constexpr int Nn = Vn * Fn;   // 16384
constexpr int Kn = Dn;        // 512
constexpr int NOT = 8;        // N-otiles per block
constexpr int GT  = (Kn / 64) * NOT;  // 64 flat K-steps per block

typedef float  f32x16 __attribute__((ext_vector_type(16)));
typedef __bf16 bf16x8 __attribute__((ext_vector_type(8)));

static __device__ __forceinline__ unsigned short f2bf(float f) {
  uint32_t x = __builtin_bit_cast(uint32_t, f);
  x += 0x7fffu + ((x >> 16) & 1u);   // round-to-nearest-even
  return (unsigned short)(x >> 16);
}

static __device__ __forceinline__ void gload_lds16(const void* g, void* l) {
  __builtin_amdgcn_global_load_lds(
      (const __attribute__((address_space(1))) uint32_t*)g,
      (__attribute__((address_space(3))) uint32_t*)l, 16, 0, 0);
}

#define BAR()   asm volatile("s_barrier" ::: "memory")
#define SBAR()  __builtin_amdgcn_sched_barrier(0)
#define LGKM(N) do { asm volatile("s_waitcnt lgkmcnt(" #N ")" ::: "memory"); \
                     SBAR(); } while (0)
#define VM6()   asm volatile("s_waitcnt vmcnt(6)" ::: "memory")
#define VM0()   asm volatile("s_waitcnt vmcnt(0)" ::: "memory")

// ---- kernel 1/2: L2-normalize rows of [R][512] f32 -> bf16 row-major ----
__global__ void normalize_rows(const float* __restrict__ src,
                               uint4* __restrict__ dst) {
  const int wave = threadIdx.x >> 6;
  const int lane = threadIdx.x & 63;
  const int row  = blockIdx.x * 4 + wave;
  const float4* p = reinterpret_cast<const float4*>(src + (size_t)row * Dn + lane * 8);
  float4 x0 = p[0];
  float4 x1 = p[1];
  float ss = x0.x*x0.x + x0.y*x0.y + x0.z*x0.z + x0.w*x0.w
           + x1.x*x1.x + x1.y*x1.y + x1.z*x1.z + x1.w*x1.w;
  #pragma unroll
  for (int m = 1; m < 64; m <<= 1) ss += __shfl_xor(ss, m, 64);
  const float inv = 1.0f / fmaxf(sqrtf(ss), 1e-12f);
  union { unsigned short u[8]; uint4 v; } pk;
  const float f[8] = {x0.x, x0.y, x0.z, x0.w, x1.x, x1.y, x1.z, x1.w};
  #pragma unroll
  for (int j = 0; j < 8; ++j) pk.u[j] = f2bf(f[j] * inv);
  dst[(size_t)row * (Dn / 8) + lane] = pk.v;
}

// ---- fused MaxSim GEMM: r5 schedule (145us, MfmaUtil 41%) + 32x32x16 MFMA ----
// 256 blocks, 1/CU; block sweeps 8 N-otiles (64 flat K-steps), 2 BAR/tile.
// Frags: af/af2 = A M-halves (2 mloc x 4 kstep), bq = B (2 nf x 4 kstep).
// 96 VGPR frags + 128 AGPR acc. Staging/swizzle identical to r5.
// MFMA 32x32x16: row/col = lane&31, k-half = lane>>5 (k-perm cancels A.B);
// C/D: col=lane&31, row=(reg&3)+8*(reg>>2)+4*(lane>>5)  [m74/m101-verified].
__global__ __launch_bounds__(512, 2)
void maxsim256_kernel(const uint16_t* __restrict__ Abf,
                      const uint16_t* __restrict__ Bbf,
                      const float* __restrict__ text,
                      const float* __restrict__ clip,
                      const float* __restrict__ logit_scale,
                      float* __restrict__ out) {
  __shared__ __align__(16) unsigned char lds[131072];
  const int tid  = threadIdx.x;
  const int lane = tid & 63;
  const int wave = tid >> 6;    // 0..7
  const int wr   = wave >> 2;   // 0..1 -> rows [wr*128, +128)
  const int wc   = wave & 3;    // 0..3 -> cols [wc*64, +64)
  const int bid  = blockIdx.x;  // 0..255
  const int nx0  = (bid & 7) * 8;   // first N-otile of this block's chunk
  const int by   = bid >> 3;        // M-tile 0..31

  const float scale = fminf(expf(logit_scale[0]), 100.0f);
  const float coefG = ALPHA_ * scale;
  const float coefL = (1.0f - ALPHA_) * scale * (1.0f / (float)Qn);

  const char* Ag  = reinterpret_cast<const char*>(Abf) + (size_t)by  * 262144;
  const char* Bg0 = reinterpret_cast<const char*>(Bbf) + (size_t)nx0 * 262144;

  // staging source offsets (identical to r5: inverse row-perm + XOR swizzle)
  unsigned srcA[2], srcB[2], ldsoff[2];
  #pragma unroll
  for (int j = 0; j < 2; ++j) {
    const unsigned r = (j * 8 + wave) * 8 + (lane >> 3);
    const unsigned c = (((lane & 7) ^ (lane >> 3)) << 4);
    srcA[j]  = (((r >> 6) << 7) + (r & 63)) * 1024 + c;  // + h*65536 + kt*128
    srcB[j]  = (((r >> 5) << 6) + (r & 31)) * 1024 + c;  // + h*32768 + kt*128
    ldsoff[j] = (j * 8 + wave) * 1024;
  }

  auto stage = [&](int buf, int isB, int h, int g) {
    const unsigned base = buf * 65536 + isB * 32768 + h * 16384;
    const unsigned kt = (g & 7) * 128;
    #pragma unroll
    for (int j = 0; j < 2; ++j) {
      const void* src = isB
          ? (const void*)(Bg0 + (size_t)((g >> 3) * 262144 + h * 32768 + kt + srcB[j]))
          : (const void*)(Ag  + (size_t)(h * 65536 + kt + srcA[j]));
      gload_lds16(src, &lds[base + ldsoff[j]]);
    }
  };

  f32x16 acc[4][2];   // [Mfrag 0..3][Nfrag 0..1] -> 128 AGPR
#define ZACC() do {                                                        \
    _Pragma("unroll") for (int i_ = 0; i_ < 4; ++i_)                       \
      _Pragma("unroll") for (int n_ = 0; n_ < 2; ++n_)                     \
        _Pragma("unroll") for (int e_ = 0; e_ < 16; ++e_)                  \
          acc[i_][n_][e_] = 0.f;                                           \
  } while (0)
  ZACC();

  bf16x8 af[2][4];    // A M-half 0 of current tile: [mloc][kstep]
  bf16x8 af2[2][4];   // A M-half 1
  bf16x8 bq[2][4];    // B: [nf][kstep]

  const int l31 = lane & 31;
  const unsigned key = (unsigned)(lane & 7) << 4;
  unsigned ck[4];
  #pragma unroll
  for (int k = 0; k < 4; ++k)
    ck[k] = (unsigned)(k * 32 + (lane >> 5) * 16) ^ key;
  const unsigned o_a32 = (unsigned)(wr * 64 + l31) * 128;  // + mloc*4096
  const unsigned o_b32 = (unsigned)(wc * 32 + l31) * 128;

// LDS A-frag read: 8 x ds_read_b128 into DST[mloc][kstep]
#define LDA(BUF, H, DST) do {                                              \
    const unsigned b_ = (unsigned)(BUF) * 65536 + (H) * 16384 + o_a32;     \
    _Pragma("unroll") for (int m_ = 0; m_ < 2; ++m_)                       \
      _Pragma("unroll") for (int k_ = 0; k_ < 4; ++k_)                     \
        DST[m_][k_] = *reinterpret_cast<const bf16x8*>(                    \
            &lds[b_ + m_ * 4096 + ck[k_]]);                                \
  } while (0)

// LDS B-frag read: 4 x ds_read_b128 into bq[NF][kstep]
#define LDB(BUF, NF) do {                                                  \
    const unsigned b_ = (unsigned)(BUF) * 65536 + 32768 + (NF) * 16384 + o_b32; \
    _Pragma("unroll") for (int k_ = 0; k_ < 4; ++k_)                       \
      bq[NF][k_] = *reinterpret_cast<const bf16x8*>(&lds[b_ + ck[k_]]);    \
  } while (0)

// 8 MFMA: M-half HM (array AF) x N-frag NF, K=64 (kstep-outer for ILP)
#define HALF(HM, AF, NF) do {                                              \
    __builtin_amdgcn_s_setprio(1);                                         \
    _Pragma("unroll") for (int k_ = 0; k_ < 4; ++k_)                       \
      _Pragma("unroll") for (int m_ = 0; m_ < 2; ++m_)                     \
        acc[(HM) * 2 + m_][NF] = __builtin_amdgcn_mfma_f32_32x32x16_bf16(  \
            AF[m_][k_], bq[NF][k_], acc[(HM) * 2 + m_][NF], 0, 0, 0);      \
    __builtin_amdgcn_s_setprio(0);                                         \
  } while (0)

// 16 MFMA: M-half HM x both N-frags (4 independent chains per kstep round)
#define HALF2(HM, AF) do {                                                 \
    __builtin_amdgcn_s_setprio(1);                                         \
    _Pragma("unroll") for (int k_ = 0; k_ < 4; ++k_)                       \
      _Pragma("unroll") for (int n_ = 0; n_ < 2; ++n_)                     \
        _Pragma("unroll") for (int m_ = 0; m_ < 2; ++m_)                   \
          acc[(HM) * 2 + m_][n_] = __builtin_amdgcn_mfma_f32_32x32x16_bf16(\
              AF[m_][k_], bq[n_][k_], acc[(HM) * 2 + m_][n_], 0, 0, 0);    \
    __builtin_amdgcn_s_setprio(0);                                         \
  } while (0)

  // per-otile epilogue. 32x32 C/D: col=lane&31, row=(reg&3)+8*(reg>>2)+4*(lane>>5)
  auto epilogue = [&](int ot) {
    const int v_out = (nx0 + ot) * 4 + wc;
    const float4* cp = reinterpret_cast<const float4*>(clip + (size_t)v_out * Dn) + lane * 2;
    const float4 c0 = cp[0], c1 = cp[1];
    #pragma unroll
    for (int mf = 0; mf < 4; ++mf) {   // Mfrag = one q-group = one t
      float s = 0.f;
      #pragma unroll
      for (int j = 0; j < 16; ++j) {   // 16 rows of this lane's k-half
        float rm = fmaxf(acc[mf][0][j], acc[mf][1][j]);   // max over 2 Nfrags
        rm = fmaxf(rm, __shfl_xor(rm, 1, 64));
        rm = fmaxf(rm, __shfl_xor(rm, 2, 64));
        rm = fmaxf(rm, __shfl_xor(rm, 4, 64));
        rm = fmaxf(rm, __shfl_xor(rm, 8, 64));
        rm = fmaxf(rm, __shfl_xor(rm, 16, 64));  // max over all 32 cols
        s += rm;                                  // sum rows of this half
      }
      s += __shfl_xor(s, 32, 64);                 // + other 16 rows -> 32 q
      const int t_out = by * 8 + wr * 4 + mf;
      const float4* tp = reinterpret_cast<const float4*>(
          text + (size_t)t_out * Dn) + lane * 2;
      const float4 t0 = tp[0], t1 = tp[1];
      float gd = t0.x*c0.x + t0.y*c0.y + t0.z*c0.z + t0.w*c0.w
               + t1.x*c1.x + t1.y*c1.y + t1.z*c1.z + t1.w*c1.w;
      gd += __shfl_xor(gd, 1, 64);  gd += __shfl_xor(gd, 2, 64);
      gd += __shfl_xor(gd, 4, 64);  gd += __shfl_xor(gd, 8, 64);
      gd += __shfl_xor(gd, 16, 64); gd += __shfl_xor(gd, 32, 64);
      if (lane == 0)
        out[t_out * Vn + v_out] = coefG * gd + coefL * s;
    }
    ZACC();
  };

  // prologue: tile0 fully + tile1 {A0,B0,B1} -> VM6 = tile0 landed
  stage(0, 0, 0, 0); stage(0, 1, 0, 0); stage(0, 1, 1, 0); stage(0, 0, 1, 0);
  stage(1, 0, 0, 1); stage(1, 1, 0, 1); stage(1, 1, 1, 1);
  VM6(); BAR();

  auto tile_step = [&](int g, int buf) {
    LDA(buf, 0, af);                       // 8 ds: A M-half 0
    LDB(buf, 0);                           // 4 ds: B nf0
    SBAR();
    LDB(buf, 1);                           // 4 ds: B nf1 (last)
    SBAR();
    if (g + 1 < GT) stage(buf ^ 1, 0, 1, g + 1);          // A1(g+1) -> other buf
    LGKM(4);                               // af + bq0 landed; bq1 in flight
    HALF(0, af, 0);                        // 8 MFMA; bq1 drains underneath
    LGKM(0);                               // bq1 landed
    HALF(0, af, 1);                        // 8 MFMA
    BAR();                                 // A0,B0,B1 slots free
    LDA(buf, 1, af2);                      // 8 ds: A M-half 1
    SBAR();
    if (g + 2 < GT) {                      // restage this buf
      stage(buf, 0, 0, g + 2);
      stage(buf, 1, 0, g + 2);
      stage(buf, 1, 1, g + 2);
    }
    LGKM(0);                               // af2 landed
    HALF2(1, af2);                         // 16 MFMA
    if (g < GT - 2) { VM6(); } else { VM0(); }             // next tile landed
    if ((g & 7) == 7) epilogue(g >> 3);                    // otile done
    BAR();
  };

  for (int t = 0; t < GT; t += 2) {
    tile_step(t, 0);
    tile_step(t + 1, 1);
  }
}

extern "C" void kernel_launch(void* const* d_in, const int* in_sizes, int n_in,
                              void* d_out, int out_size, void* d_ws, size_t ws_size,
                              hipStream_t stream) {
  const float* text        = (const float*)d_in[0];
  const float* clip        = (const float*)d_in[1];
  const float* concept     = (const float*)d_in[2];
  const float* frames      = (const float*)d_in[3];
  const float* logit_scale = (const float*)d_in[4];
  float* out = (float*)d_out;

  uint16_t* Abf = (uint16_t*)d_ws;              //  8192*512 bf16 = 8 MiB
  uint16_t* Bbf = Abf + (size_t)Mn * Kn;        // 16384*512 bf16 = 16 MiB

  normalize_rows<<<Mn / 4, 256, 0, stream>>>(concept, (uint4*)Abf);
  normalize_rows<<<Nn / 4, 256, 0, stream>>>(frames, (uint4*)Bbf);
  maxsim256_kernel<<<256, 512, 0, stream>>>(Abf, Bbf, text, clip, logit_scale, out);
}